// Round 2
// baseline (162.184 us; speedup 1.0000x reference)
//
#include <hip/hip_runtime.h>

// Encoding layer, fused. B=32, C=256, K=32, N=4096.
// ws layout (floats): wx[32*32*256] @0 | wsum[32*32] @262144 | abp[96] @263168 | cw2t[4096 u32] @263264

#define CC 256
#define KK 32
#define NN 4096
#define CN (CC*NN)
#define CHUNK 64
#define NCHUNK 2
#define BPB 32   // blocks per batch -> 1024 blocks, 128 tokens each

typedef unsigned int u32;
typedef unsigned short u16;
typedef __fp16 half2_t __attribute__((ext_vector_type(2)));

__device__ __forceinline__ u32 pack2(float a, float b) {
    half2_t h = __builtin_amdgcn_cvt_pkrtz(a, b);
    u32 u;
    __builtin_memcpy(&u, &h, 4);
    return u;
}

__device__ __forceinline__ float fdot2u(u32 a, u32 b, float c) {
    half2_t ha, hb;
    __builtin_memcpy(&ha, &a, 4);
    __builtin_memcpy(&hb, &b, 4);
#if __has_builtin(__builtin_amdgcn_fdot2)
    return __builtin_amdgcn_fdot2(ha, hb, c, false);
#else
    return c + (float)ha[0] * (float)hb[0] + (float)ha[1] * (float)hb[1];
#endif
}

// ---------------- prep: c_sq/scale tables + fp16-pair-packed codewords (transposed) ----------------
__global__ void enc_prep(const float* __restrict__ cw, const float* __restrict__ scale,
                         float* __restrict__ abp, u32* __restrict__ cw2t) {
    int tid = threadIdx.x;
    // c_sq: k = tid>>3, 8 partial lanes each sum 32 elems
    {
        int k = tid >> 3, p = tid & 7;
        float s = 0.f;
        #pragma unroll
        for (int i = 0; i < 32; ++i) {
            float v = cw[k * 256 + p * 32 + i];
            s += v * v;
        }
        s += __shfl_xor(s, 1);
        s += __shfl_xor(s, 2);
        s += __shfl_xor(s, 4);
        if (p == 0) {
            float A = scale[k];
            abp[k]      = A;          // A_k
            abp[32 + k] = A * s;      // A_k * csq_k
            abp[64 + k] = -2.f * A;   // P_k
        }
    }
    // cw2t[cp*32 + k] = (h(cw[k][2cp]), h(cw[k][2cp+1]))
    for (int it = 0; it < 16; ++it) {
        int idx = it * 256 + tid;
        int cp = idx >> 5, k = idx & 31;
        cw2t[idx] = pack2(cw[k * 256 + 2 * cp], cw[k * 256 + 2 * cp + 1]);
    }
}

// ---------------- fused main ----------------
__global__ __launch_bounds__(256, 2) void enc_main(
    const float* __restrict__ x, const u32* __restrict__ cw2t,
    const float* __restrict__ abp, float* __restrict__ wx, float* __restrict__ wsum) {

    __shared__ u32   xt[CC * 34];   // [c][tp] fp16 t-pairs, stride 34 -> conflict-free b64 column reads
    __shared__ float sc[64 * 32];   // xc exchange, XOR-swizzled: idx = t*32 + ((k&~3)^((t&7)<<2)) + (k&3)
    __shared__ u16   w2s[KK * 64];  // w fp16 [k][t], idx = k*64 + (t ^ ((k>>3)<<4))

    const int tid = threadIdx.x;
    const int w   = tid >> 6;
    const int l   = tid & 63;
    const int b   = blockIdx.x >> 5;
    const int blk = blockIdx.x & 31;
    const int wu  = __builtin_amdgcn_readfirstlane(w);  // uniform wave id -> s_load for codewords

    // pass-B accumulators: wave owns k = wu*8+j ; lane owns c = l + 64*q
    float acc[8][4];
    #pragma unroll
    for (int j = 0; j < 8; ++j)
        #pragma unroll
        for (int q = 0; q < 4; ++q) acc[j][q] = 0.f;
    float wsacc[8];
    #pragma unroll
    for (int j = 0; j < 8; ++j) wsacc[j] = 0.f;

    // softmax-side per-k constants (softmax mapping: koct = l>>4)
    const int koct = l >> 4;
    float Ak[8], Bk[8], Pk[8];
    #pragma unroll
    for (int j = 0; j < 8; ++j) {
        int k = koct * 8 + j;
        Ak[j] = abp[k]; Bk[j] = abp[32 + k]; Pk[j] = abp[64 + k];
    }

    for (int ch = 0; ch < NCHUNK; ++ch) {
        const int n0 = blk * (CHUNK * NCHUNK) + ch * CHUNK;

        // ---- pass A: xc[k] for k = wu*8..+7, token t = n0 + l (lane = token) ----
        const float* xg = x + (size_t)b * CN + n0 + l;
        float xc[8];
        #pragma unroll
        for (int j = 0; j < 8; ++j) xc[j] = 0.f;
        float xsq = 0.f;
        #pragma unroll 4
        for (int cp = 0; cp < 128; ++cp) {
            float v0 = xg[(2 * cp) * NN];
            float v1 = xg[(2 * cp + 1) * NN];
            xsq += v0 * v0 + v1 * v1;            // fp32-exact x_sq
            u32 xv = pack2(v0, v1);
            const uint4* cwp = (const uint4*)(cw2t + cp * 32 + wu * 8);  // uniform -> SMEM
            uint4 ca = cwp[0], cb = cwp[1];
            xc[0] = fdot2u(xv, ca.x, xc[0]);
            xc[1] = fdot2u(xv, ca.y, xc[1]);
            xc[2] = fdot2u(xv, ca.z, xc[2]);
            xc[3] = fdot2u(xv, ca.w, xc[3]);
            xc[4] = fdot2u(xv, cb.x, xc[4]);
            xc[5] = fdot2u(xv, cb.y, xc[5]);
            xc[6] = fdot2u(xv, cb.z, xc[6]);
            xc[7] = fdot2u(xv, cb.w, xc[7]);
        }
        {   // exchange xc -> sc (t = l, k = wu*8+j), XOR-swizzled float4 pair
            int xr = (l & 7) << 2;
            float4 lo = make_float4(xc[0], xc[1], xc[2], xc[3]);
            float4 hi = make_float4(xc[4], xc[5], xc[6], xc[7]);
            *(float4*)&sc[l * 32 + ((wu * 8)     ^ xr)] = lo;
            *(float4*)&sc[l * 32 + ((wu * 8 + 4) ^ xr)] = hi;
        }
        __syncthreads();  // bar1

        // ---- softmax: thread = (koct, t_s = w*16 + (tid&15)) ----
        const int ts = w * 16 + (tid & 15);
        float xsq_t = __shfl(xsq, ts);  // lane==token in pass-A mapping
        float lg[8];
        {
            int xr = (ts & 7) << 2;
            float4 lo = *(const float4*)&sc[ts * 32 + ((koct * 8)     ^ xr)];
            float4 hi = *(const float4*)&sc[ts * 32 + ((koct * 8 + 4) ^ xr)];
            lg[0] = lo.x; lg[1] = lo.y; lg[2] = lo.z; lg[3] = lo.w;
            lg[4] = hi.x; lg[5] = hi.y; lg[6] = hi.z; lg[7] = hi.w;
        }
        float m = -3.4e38f;
        #pragma unroll
        for (int j = 0; j < 8; ++j) {
            lg[j] = Ak[j] * xsq_t + Bk[j] + Pk[j] * lg[j];  // scale_k*(xsq - 2xc + csq)
            m = fmaxf(m, lg[j]);
        }
        m = fmaxf(m, __shfl_xor(m, 16));
        m = fmaxf(m, __shfl_xor(m, 32));
        float e[8], s = 0.f;
        #pragma unroll
        for (int j = 0; j < 8; ++j) { e[j] = __expf(lg[j] - m); s += e[j]; }
        s += __shfl_xor(s, 16);
        s += __shfl_xor(s, 32);
        float r = 1.0f / s;
        #pragma unroll
        for (int j = 0; j < 8; ++j) {
            float wv = e[j] * r;
            wsacc[j] += wv;
            union { __fp16 h; u16 us; } cv;
            cv.h = (__fp16)wv;
            w2s[(koct * 8 + j) * 64 + (ts ^ (koct << 4))] = cv.us;
        }
        __syncthreads();  // bar2

        // ---- stage x -> LDS fp16 t-pairs (global is L1/L2-hot from pass A) ----
        #pragma unroll 4
        for (int it = 0; it < 32; ++it) {
            int c = it * 8 + w * 2 + (l >> 5);
            const float2* xs = (const float2*)(x + (size_t)b * CN + (size_t)c * NN + n0);
            float2 v = xs[l & 31];
            xt[c * 34 + (l & 31)] = pack2(v.x, v.y);
        }
        __syncthreads();  // bar3

        // ---- pass B: acc[k][c] += sum_t w[t][k] * x[t][c] via dot2 on t-pairs ----
        #pragma unroll 2
        for (int tg = 0; tg < 8; ++tg) {
            uint4 wv[8];
            #pragma unroll
            for (int j = 0; j < 8; ++j)
                wv[j] = *(const uint4*)&w2s[(wu * 8 + j) * 64 + ((tg * 8) ^ (wu << 4))];
            #pragma unroll
            for (int q = 0; q < 4; ++q) {
                int c = l + 64 * q;
                const uint2* xp = (const uint2*)&xt[c * 34 + tg * 4];
                uint2 r0 = xp[0], r1 = xp[1];
                #pragma unroll
                for (int j = 0; j < 8; ++j) {
                    acc[j][q] = fdot2u(r0.x, wv[j].x, acc[j][q]);
                    acc[j][q] = fdot2u(r0.y, wv[j].y, acc[j][q]);
                    acc[j][q] = fdot2u(r1.x, wv[j].z, acc[j][q]);
                    acc[j][q] = fdot2u(r1.y, wv[j].w, acc[j][q]);
                }
            }
        }
        // no barrier needed here: next writes to sc/xt/w2s are gated by bar1/bar2 of next chunk
    }

    // ---- epilogue: wsum (reduce 16 token-lanes) + wx atomics ----
    #pragma unroll
    for (int j = 0; j < 8; ++j) {
        float v = wsacc[j];
        v += __shfl_xor(v, 1);
        v += __shfl_xor(v, 2);
        v += __shfl_xor(v, 4);
        v += __shfl_xor(v, 8);
        if ((tid & 15) == 0)
            atomicAdd(&wsum[b * KK + koct * 8 + j], v);
    }
    #pragma unroll
    for (int j = 0; j < 8; ++j)
        #pragma unroll
        for (int q = 0; q < 4; ++q)
            atomicAdd(&wx[(size_t)b * 8192 + (wu * 8 + j) * 256 + (l + 64 * q)], acc[j][q]);
}

// ---------------- finalize: out = wx - wsum*c ----------------
__global__ void enc_final(const float* __restrict__ wx, const float* __restrict__ wsum,
                          const float* __restrict__ cw, float* __restrict__ out) {
    int i = blockIdx.x * 256 + threadIdx.x;
    int c = i & 255, k = (i >> 8) & 31, b = i >> 13;
    out[i] = wx[i] - wsum[b * 32 + k] * cw[k * 256 + c];
}

extern "C" void kernel_launch(void* const* d_in, const int* in_sizes, int n_in,
                              void* d_out, int out_size, void* d_ws, size_t ws_size,
                              hipStream_t stream) {
    (void)in_sizes; (void)n_in; (void)out_size; (void)ws_size;
    const float* x     = (const float*)d_in[0];
    const float* cw    = (const float*)d_in[1];
    const float* scale = (const float*)d_in[2];
    float* out = (float*)d_out;

    float* wsf   = (float*)d_ws;
    float* wx    = wsf;                 // 262144 f32
    float* wsum  = wsf + 262144;        // 1024 f32
    float* abp   = wsf + 263168;        // 96 f32
    u32*   cw2t  = (u32*)(wsf + 263264); // 4096 u32

    (void)hipMemsetAsync(d_ws, 0, 263168 * sizeof(float), stream);  // zero wx + wsum
    hipLaunchKernelGGL(enc_prep,  dim3(1),    dim3(256), 0, stream, cw, scale, abp, cw2t);
    hipLaunchKernelGGL(enc_main,  dim3(1024), dim3(256), 0, stream, x, cw2t, abp, wx, wsum);
    hipLaunchKernelGGL(enc_final, dim3(1024), dim3(256), 0, stream, wx, wsum, cw, out);
}

// Round 4
// 112.547 us; speedup vs baseline: 1.4410x; 1.4410x over previous
//
#include <hip/hip_runtime.h>

// Encoding layer, fused. B=32, C=256, K=32, N=4096.
// R4: R3 design + fixed wsum reduction (was reading 16/32 tokens per segment).
// ws layout (floats): wx[262144] @0 | wsum[1024] @262144 | abp4[128] @263168 | cw2t[4096 u32] @263296

#define CC 256
#define KK 32
#define NN 4096
#define CN (CC*NN)
#define TPB 256    // tokens per block == threads per block

typedef unsigned int u32;
typedef unsigned short u16;
typedef __fp16 half2_t __attribute__((ext_vector_type(2)));

__device__ __forceinline__ u32 pack2(float a, float b) {
    half2_t h = __builtin_amdgcn_cvt_pkrtz(a, b);
    u32 u;
    __builtin_memcpy(&u, &h, 4);
    return u;
}

__device__ __forceinline__ float fdot2u(u32 a, u32 b, float c) {
    half2_t ha, hb;
    __builtin_memcpy(&ha, &a, 4);
    __builtin_memcpy(&hb, &b, 4);
#if __has_builtin(__builtin_amdgcn_fdot2)
    return __builtin_amdgcn_fdot2(ha, hb, c, false);
#else
    return c + (float)ha[0] * (float)hb[0] + (float)ha[1] * (float)hb[1];
#endif
}

// ---------------- prep: per-k logit constants + fp16-pair-packed codewords [cp][k] ----------------
__global__ void enc_prep(const float* __restrict__ cw, const float* __restrict__ scale,
                         float* __restrict__ abp4, u32* __restrict__ cw2t) {
    int tid = threadIdx.x;
    {
        int k = tid >> 3, p = tid & 7;
        float s = 0.f;
        #pragma unroll
        for (int i = 0; i < 32; ++i) {
            float v = cw[k * 256 + p * 32 + i];
            s += v * v;
        }
        s += __shfl_xor(s, 1);
        s += __shfl_xor(s, 2);
        s += __shfl_xor(s, 4);
        if (p == 0) {
            float A = scale[k];
            abp4[k * 4 + 0] = A;          // A_k
            abp4[k * 4 + 1] = A * s;      // A_k * csq_k
            abp4[k * 4 + 2] = -2.f * A;   // P_k
            abp4[k * 4 + 3] = 0.f;
        }
    }
    // cw2t[cp*32 + k] = (h(cw[k][2cp]), h(cw[k][2cp+1]))
    for (int it = 0; it < 16; ++it) {
        int idx = it * 256 + tid;
        int cp = idx >> 5, k = idx & 31;
        cw2t[idx] = pack2(cw[k * 256 + 2 * cp], cw[k * 256 + 2 * cp + 1]);
    }
}

// ---------------- fused main: 512 blocks x 256 threads ----------------
__global__ __launch_bounds__(256) void enc_main(
    const float* __restrict__ x, const u32* __restrict__ cw2t,
    const float* __restrict__ abp4, float* __restrict__ wx, float* __restrict__ wsum) {

    __shared__ u32 xt[CC * 36];   // [c][tp] fp16 t-pairs (64-t sub-chunk), stride 36 -> 16B-aligned b128, 2-way max
    __shared__ u16 w2s[KK * TPB]; // [k][t] fp16 weights for all 256 tokens

    const int tid = threadIdx.x;
    const int l   = tid & 63;
    const int b   = blockIdx.x >> 4;
    const int blk = blockIdx.x & 15;
    const int n0  = blk * TPB;
    const int wu  = __builtin_amdgcn_readfirstlane(tid >> 6);

    // ================= pass A: lane = token, xc[k] for all 32 k =================
    const float* xg = x + (size_t)b * CN + n0 + tid;
    float xc[32];
    #pragma unroll
    for (int k = 0; k < 32; ++k) xc[k] = 0.f;
    float xsq = 0.f;

    // software-pipelined: batches of 4 c-pairs (8 channels), double-buffered
    float va[8], vb[8];
    #pragma unroll
    for (int j = 0; j < 8; ++j) va[j] = xg[(size_t)j * NN];

    #define CONSUME(V, BB)                                                     \
        {                                                                      \
            _Pragma("unroll")                                                  \
            for (int i = 0; i < 4; ++i) {                                      \
                float v0 = V[2 * i], v1 = V[2 * i + 1];                        \
                xsq += v0 * v0 + v1 * v1;                                      \
                u32 xv = pack2(v0, v1);                                        \
                const u32* cwr = cw2t + ((BB) * 4 + i) * 32;                   \
                _Pragma("unroll")                                              \
                for (int k = 0; k < 32; ++k)                                   \
                    xc[k] = fdot2u(xv, cwr[k], xc[k]);                         \
            }                                                                  \
        }

    for (int bb = 0; bb < 32; bb += 2) {
        #pragma unroll
        for (int j = 0; j < 8; ++j) vb[j] = xg[(size_t)((bb + 1) * 8 + j) * NN];
        CONSUME(va, bb);
        if (bb < 30) {
            #pragma unroll
            for (int j = 0; j < 8; ++j) va[j] = xg[(size_t)((bb + 2) * 8 + j) * NN];
        }
        CONSUME(vb, bb + 1);
    }
    #undef CONSUME

    // ================= softmax: fully lane-local over 32 k =================
    {
        const float4* ap = (const float4*)abp4;
        float m = -3.4e38f;
        #pragma unroll
        for (int k = 0; k < 32; ++k) {
            float4 t = ap[k];
            xc[k] = fmaf(t.x, xsq, t.y) + t.z * xc[k];   // A*xsq + A*csq - 2A*xc
            m = fmaxf(m, xc[k]);
        }
        float s = 0.f;
        #pragma unroll
        for (int k = 0; k < 32; ++k) { xc[k] = __expf(xc[k] - m); s += xc[k]; }
        float r = 1.0f / s;
        #pragma unroll
        for (int k = 0; k < 32; ++k) {
            union { __fp16 h; u16 us; } cv;
            cv.h = (__fp16)(xc[k] * r);
            w2s[k * TPB + tid] = cv.us;   // per instr: 64 contiguous u16 -> conflict-free
        }
    }
    __syncthreads();  // w2s ready

    // ================= wsum: reduce w2s rows (8 lanes x 32 tokens per k) =================
    {
        int k = tid >> 3, seg = tid & 7;
        const uint4* wp = (const uint4*)&w2s[k * TPB + seg * 32];
        uint4 a0 = wp[0], a1 = wp[1], a2 = wp[2], a3 = wp[3];  // 32 tokens
        const u32 ONES = 0x3C003C00u;  // (1.0h, 1.0h)
        float s = 0.f;
        s = fdot2u(a0.x, ONES, s); s = fdot2u(a0.y, ONES, s);
        s = fdot2u(a0.z, ONES, s); s = fdot2u(a0.w, ONES, s);
        s = fdot2u(a1.x, ONES, s); s = fdot2u(a1.y, ONES, s);
        s = fdot2u(a1.z, ONES, s); s = fdot2u(a1.w, ONES, s);
        s = fdot2u(a2.x, ONES, s); s = fdot2u(a2.y, ONES, s);
        s = fdot2u(a2.z, ONES, s); s = fdot2u(a2.w, ONES, s);
        s = fdot2u(a3.x, ONES, s); s = fdot2u(a3.y, ONES, s);
        s = fdot2u(a3.z, ONES, s); s = fdot2u(a3.w, ONES, s);
        s += __shfl_xor(s, 1);
        s += __shfl_xor(s, 2);
        s += __shfl_xor(s, 4);
        if (seg == 0) atomicAdd(&wsum[b * KK + k], s);
    }

    // ================= pass B: 4 sub-chunks of 64 tokens =================
    float acc[8][4];
    #pragma unroll
    for (int j = 0; j < 8; ++j)
        #pragma unroll
        for (int q = 0; q < 4; ++q) acc[j][q] = 0.f;

    for (int s = 0; s < 4; ++s) {
        const int t0 = s * 64;
        // stage x[c][t0..t0+63] -> xt fp16 t-pairs, coalesced float2 rows
        #pragma unroll 4
        for (int it = 0; it < 32; ++it) {
            int c = it * 8 + (tid >> 5);
            const float2* xs = (const float2*)(x + (size_t)b * CN + (size_t)c * NN + n0 + t0);
            float2 v = xs[tid & 31];
            xt[c * 36 + (tid & 31)] = pack2(v.x, v.y);
        }
        __syncthreads();  // xt ready (also gates w2s for first consume)

        // consume: wave wu owns k-octet, lane covers c = (tid&63) + 64q
        #pragma unroll
        for (int tg = 0; tg < 8; ++tg) {
            uint4 wf[8];
            #pragma unroll
            for (int j = 0; j < 8; ++j)
                wf[j] = *(const uint4*)&w2s[(wu * 8 + j) * TPB + t0 + tg * 8];  // uniform -> broadcast
            #pragma unroll
            for (int q = 0; q < 4; ++q) {
                int c = l + 64 * q;
                uint4 xv4 = *(const uint4*)&xt[c * 36 + tg * 4];
                #pragma unroll
                for (int j = 0; j < 8; ++j) {
                    acc[j][q] = fdot2u(xv4.x, wf[j].x, acc[j][q]);
                    acc[j][q] = fdot2u(xv4.y, wf[j].y, acc[j][q]);
                    acc[j][q] = fdot2u(xv4.z, wf[j].z, acc[j][q]);
                    acc[j][q] = fdot2u(xv4.w, wf[j].w, acc[j][q]);
                }
            }
        }
        __syncthreads();  // consume done before next stage overwrites xt
    }

    // ================= epilogue: wx atomics =================
    #pragma unroll
    for (int j = 0; j < 8; ++j)
        #pragma unroll
        for (int q = 0; q < 4; ++q)
            atomicAdd(&wx[(size_t)b * 8192 + (wu * 8 + j) * 256 + (l + 64 * q)], acc[j][q]);
}

// ---------------- finalize: out = wx - wsum*c ----------------
__global__ void enc_final(const float* __restrict__ wx, const float* __restrict__ wsum,
                          const float* __restrict__ cw, float* __restrict__ out) {
    int i = blockIdx.x * 256 + threadIdx.x;
    int c = i & 255, k = (i >> 8) & 31, b = i >> 13;
    out[i] = wx[i] - wsum[b * 32 + k] * cw[k * 256 + c];
}

extern "C" void kernel_launch(void* const* d_in, const int* in_sizes, int n_in,
                              void* d_out, int out_size, void* d_ws, size_t ws_size,
                              hipStream_t stream) {
    (void)in_sizes; (void)n_in; (void)out_size; (void)ws_size;
    const float* x     = (const float*)d_in[0];
    const float* cw    = (const float*)d_in[1];
    const float* scale = (const float*)d_in[2];
    float* out = (float*)d_out;

    float* wsf   = (float*)d_ws;
    float* wx    = wsf;                  // 262144 f32
    float* wsum  = wsf + 262144;         // 1024 f32
    float* abp4  = wsf + 263168;         // 128 f32
    u32*   cw2t  = (u32*)(wsf + 263296); // 4096 u32

    (void)hipMemsetAsync(d_ws, 0, 263168 * sizeof(float), stream);  // zero wx + wsum
    hipLaunchKernelGGL(enc_prep,  dim3(1),    dim3(256), 0, stream, cw, scale, abp4, cw2t);
    hipLaunchKernelGGL(enc_main,  dim3(512),  dim3(256), 0, stream, x, cw2t, abp4, wx, wsum);
    hipLaunchKernelGGL(enc_final, dim3(1024), dim3(256), 0, stream, wx, wsum, cw, out);
}